// Round 10
// baseline (93.323 us; speedup 1.0000x reference)
//
#include <hip/hip_runtime.h>
#include <hip/hip_bf16.h>
#include <math.h>

#define N_ROWS 32768
#define C_DIM 256
#define K_CODES 1024
#define DECAY_F 0.99f
#define ONE_MINUS_DECAY 0.01f
#define EPS_F 1e-5f

// Output offsets (floats)
#define OFF_QST 0
#define OFF_EMB 8388608
#define OFF_CS  8650752
#define OFF_DW  8651776
#define OFF_LOSS 8913920
#define OFF_PERP 8913921

// Workspace layout (float offsets)
#define WS_ESQ   0         // 1024
#define WS_BP    1024      // 131072 floats = 512KB bf16-packed E
#define WS_DWT   132096    // 262144  dwT[k][c]
#define WS_CNT   394240    // 1024
#define WS_LOSSP 395264    // 1024
#define WS_INVSM 396288    // 1024
#define WS_IDX   397312    // 32768 ints

typedef __attribute__((ext_vector_type(8))) short bf16x8;
typedef __attribute__((ext_vector_type(4))) float f32x4;
typedef union { short s[8]; unsigned u[4]; bf16x8 v; } fragu;

#define GLD_LDS16(g, l) __builtin_amdgcn_global_load_lds( \
    (const __attribute__((address_space(1))) void*)(g),   \
    (__attribute__((address_space(3))) void*)(l), 16, 0, 0)

__device__ inline unsigned bf16rne(float f) {
    unsigned u = __float_as_uint(f);
    return (u + 0x7fffu + ((u >> 16) & 1u)) >> 16;
}

__device__ inline unsigned pack_bf16_pair(float a, float b) {
    float2 f2; f2.x = a; f2.y = b;
    __hip_bfloat162 h = __float22bfloat162_rn(f2);   // v_cvt_pk_bf16_f32
    union { __hip_bfloat162 b2; unsigned u; } cv;
    cv.b2 = h;
    return cv.u;
}

// ---------------- prep (fused): pack E into MFMA B layout + esq ----------
// Blocks 0..127: b_pack. Group g = ct*8 + ks; lane l: 8 bf16,
// col = ct*16+(l&15), k = ks*32 + (l>>4)*8 + b.
// Blocks 128..131: esq[k] = sum_d E[d,k]^2 (fp32 exact).
__global__ __launch_bounds__(256) void prep_kernel(const float* __restrict__ E,
                                                   short* __restrict__ Bp,
                                                   float* __restrict__ esq) {
    int tid = threadIdx.x;
    int b = blockIdx.x;
    if (b < 128) {
        int g = b * 4 + (tid >> 6);
        int l = tid & 63;
        int ct = g >> 3, ks = g & 7;
        int j = ct * 16 + (l & 15);
        int kbase = ks * 32 + (l >> 4) * 8;
        fragu out;
        #pragma unroll
        for (int q = 0; q < 8; ++q)
            out.s[q] = (short)bf16rne(E[(kbase + q) * K_CODES + j]);
        *(bf16x8*)(Bp + ((size_t)g * 64 + l) * 8) = out.v;
    } else {
        int k = (b - 128) * 256 + tid;
        float s = 0.f;
        #pragma unroll 8
        for (int d = 0; d < C_DIM; ++d) {
            float e = E[d * K_CODES + k];
            s += e * e;
        }
        esq[k] = s;
    }
}

// ---------------- MFMA distance + fused argmax (block-complete) ----------
// 512 blocks x 8 waves (512 thr). Block = 64 rows x ALL 1024 cols ->
// argmax finishes in-block, idx written as plain int (no atomics).
// Wave (rg=w>>2, qt=w&3): rows rg*32..+31 (rt=2 tiles), cols qt*256..+255.
// Phase p = cc*8+ks (cc 0..3 = 64-col chunk/quarter, ks 0..7): stage =
// 16 groups x 1KB = 16KB (4 qt x 4 ct) into 4-slot ring, depth-2 in flight,
// vmcnt(4), ONE barrier/phase. Each group is read by the 2 rg-waves of its qt.
__global__ __launch_bounds__(512, 4) void mfma_dist_kernel(
    const float* __restrict__ X,
    const short* __restrict__ Bp,
    const float* __restrict__ esq,
    int* __restrict__ idxbuf)
{
    __shared__ short sB[4][8192];    // 4 x 16KB ring
    __shared__ float sval[8][32];
    __shared__ int   sidx[8][32];

    int tid = threadIdx.x;
    int w = tid >> 6, l = tid & 63;
    int rg = w >> 2;          // row group 0..1
    int qt = w & 3;           // col quarter 0..3
    int row0 = blockIdx.x * 64;
    int arow = l & 15;
    int aseg = l >> 4;
    const float* Xr0 = X + (size_t)(row0 + rg * 32 + arow) * C_DIM + aseg * 8;
    const float* Xr1 = Xr0 + 16 * C_DIM;

    // stage phase (cc_,ks_) into ring slot sl: 2 loads/thread; g = i*8+w
    // in 0..15: quarter qt_=g>>2, sub-tile j=g&3; ct = qt_*16 + cc_*4 + j.
#define STAGE(cc_, ks_, sl) do {                                             \
        _Pragma("unroll")                                                    \
        for (int i = 0; i < 2; ++i) {                                        \
            int g = i * 8 + w;                                               \
            int ct = (g >> 2) * 16 + (cc_) * 4 + (g & 3);                    \
            const short* src = Bp + ((size_t)(ct * 8 + (ks_)) * 64 + l) * 8; \
            GLD_LDS16(src, &sB[sl][g * 512]);                                \
        }                                                                    \
    } while (0)

    // prologue: stages for phases 0,1
    STAGE(0, 0, 0);
    STAGE(0, 1, 1);

    // load + convert all A fragments once; compiler waits on these X loads
    // drain vmcnt fully, so stages 0,1 are retired before the phase loop.
    bf16x8 ahs0[8], ahs1[8];
    #pragma unroll
    for (int ks = 0; ks < 8; ++ks) {
        float xf0[8], xf1[8];
        *(float4*)(xf0)     = *(const float4*)(Xr0 + ks * 32);
        *(float4*)(xf0 + 4) = *(const float4*)(Xr0 + ks * 32 + 4);
        *(float4*)(xf1)     = *(const float4*)(Xr1 + ks * 32);
        *(float4*)(xf1 + 4) = *(const float4*)(Xr1 + ks * 32 + 4);
        fragu a0, a1;
        #pragma unroll
        for (int p = 0; p < 4; ++p) {
            a0.u[p] = pack_bf16_pair(xf0[2 * p], xf0[2 * p + 1]);
            a1.u[p] = pack_bf16_pair(xf1[2 * p], xf1[2 * p + 1]);
        }
        ahs0[ks] = a0.v;
        ahs1[ks] = a1.v;
    }

    float best[8];
    int bidx[8];
    #pragma unroll
    for (int i = 0; i < 8; ++i) { best[i] = -INFINITY; bidx[i] = 0; }

    #pragma unroll
    for (int cc = 0; cc < 4; ++cc) {
        f32x4 acc[2][4];
        #pragma unroll
        for (int rt = 0; rt < 2; ++rt)
            #pragma unroll
            for (int j = 0; j < 4; ++j)
                acc[rt][j] = (f32x4)(0.f);

        #pragma unroll
        for (int ks = 0; ks < 8; ++ks) {
            const int p = cc * 8 + ks;
            const int slot = p & 3;
            // issue stage p+2 (slot (p+2)&3 was last read at phase p-2,
            // whose reads completed before every wave crossed barrier p-1)
            if (p < 30) {
                const int pn = p + 2;
                STAGE(pn >> 3, pn & 7, pn & 3);
                asm volatile("s_waitcnt vmcnt(4)" ::: "memory");
            } else if (p == 30) {
                asm volatile("s_waitcnt vmcnt(2)" ::: "memory");
            } else {
                asm volatile("s_waitcnt vmcnt(0)" ::: "memory");
            }
            __builtin_amdgcn_s_barrier();   // publishes stage p to all waves
            asm volatile("" ::: "memory");

            const short* lbase = &sB[slot][(qt * 4) * 512 + l * 8];
            __builtin_amdgcn_s_setprio(1);
            #pragma unroll
            for (int j = 0; j < 4; ++j) {
                bf16x8 bh = *(const bf16x8*)(lbase + j * 512);
                acc[0][j] = __builtin_amdgcn_mfma_f32_16x16x32_bf16(ahs0[ks], bh, acc[0][j], 0, 0, 0);
                acc[1][j] = __builtin_amdgcn_mfma_f32_16x16x32_bf16(ahs1[ks], bh, acc[1][j], 0, 0, 0);
            }
            __builtin_amdgcn_s_setprio(0);
        }
        // epilogue for this 64-col chunk of our quarter (registers only)
        #pragma unroll
        for (int rt = 0; rt < 2; ++rt) {
            #pragma unroll
            for (int j = 0; j < 4; ++j) {
                int col = qt * 256 + cc * 64 + j * 16 + (l & 15);
                float sq = esq[col];
                #pragma unroll
                for (int v = 0; v < 4; ++v) {
                    float s2 = 2.f * acc[rt][j][v] - sq;
                    int bi = rt * 4 + v;
                    if (s2 > best[bi]) { best[bi] = s2; bidx[bi] = col; }
                }
            }
        }
    }
#undef STAGE

    // reduce across the 16 lanes holding different cols of the same rows
    #pragma unroll
    for (int bi = 0; bi < 8; ++bi) {
        float bv = best[bi]; int ix = bidx[bi];
        #pragma unroll
        for (int m = 1; m < 16; m <<= 1) {
            float ov = __shfl_xor(bv, m, 64);
            int oi = __shfl_xor(ix, m, 64);
            if (ov > bv || (ov == bv && oi < ix)) { bv = ov; ix = oi; }
        }
        if ((l & 15) == 0) {
            int rt = bi >> 2, v = bi & 3;
            sval[w][rt * 16 + aseg * 4 + v] = bv;
            sidx[w][rt * 16 + aseg * 4 + v] = ix;
        }
    }
    __syncthreads();
    // merge 4 col-quarters per row group; qt ascending => lowest col on ties
    if (tid < 64) {
        int r = tid & 31;
        int g2 = tid >> 5;                 // row group
        float bv = sval[g2 * 4][r];
        int ix = sidx[g2 * 4][r];
        #pragma unroll
        for (int q2 = 1; q2 < 4; ++q2) {
            float ov = sval[g2 * 4 + q2][r];
            int oi = sidx[g2 * 4 + q2][r];
            if (ov > bv) { bv = ov; ix = oi; }
        }
        idxbuf[row0 + g2 * 32 + r] = ix;
    }
}

// ---------------- per-code: quant_st, dw, counts, loss (no fp atomics) ----
#define QCAP 2048
__global__ __launch_bounds__(256) void percode_kernel(
    const float* __restrict__ X,
    const float* __restrict__ E,
    const int* __restrict__ idxbuf,
    float* __restrict__ out_qst,
    float* __restrict__ dwT,
    float* __restrict__ counts,
    float* __restrict__ lossp)
{
    __shared__ int queue[4][QCAP];
    __shared__ float redA[4][256];
    __shared__ float redL[4];
    __shared__ int redC[4];

    int k = blockIdx.x;
    int tid = threadIdx.x;
    int w = tid >> 6, lane = tid & 63;

    float q0 = E[(lane * 4 + 0) * K_CODES + k];
    float q1 = E[(lane * 4 + 1) * K_CODES + k];
    float q2 = E[(lane * 4 + 2) * K_CODES + k];
    float q3 = E[(lane * 4 + 3) * K_CODES + k];

    const float4* X4 = (const float4*)X;
    float4* O4 = (float4*)out_qst;
    const int4* I4 = (const int4*)idxbuf;

    float a0 = 0.f, a1 = 0.f, a2 = 0.f, a3 = 0.f, ls = 0.f;
    int tot = 0, cnt = 0;
    unsigned long long below_mask = (lane == 0) ? 0ull : (~0ull >> (64 - lane));

#define DRAIN() do {                                                        \
        for (int qi = 0; qi < cnt; ++qi) {                                  \
            int row = queue[w][qi];                                         \
            float4 x = X4[(size_t)row * 64 + lane];                         \
            float d0 = q0 - x.x, d1 = q1 - x.y, d2 = q2 - x.z, d3 = q3 - x.w; \
            float4 o; o.x = x.x + d0; o.y = x.y + d1;                       \
            o.z = x.z + d2; o.w = x.w + d3;                                 \
            O4[(size_t)row * 64 + lane] = o;                                \
            a0 += x.x; a1 += x.y; a2 += x.z; a3 += x.w;                     \
            ls += d0 * d0 + d1 * d1 + d2 * d2 + d3 * d3;                    \
        }                                                                   \
        tot += cnt; cnt = 0;                                                \
    } while (0)

    int base = w * 2048;   // int4 units; wave quarter = 8192 ints
    for (int it = 0; it < 32; ++it) {
        int4 v = I4[base + it * 64 + lane];
        int rbase = (base + it * 64 + lane) * 4;
        #pragma unroll
        for (int j = 0; j < 4; ++j) {
            int vj = (j == 0) ? v.x : (j == 1) ? v.y : (j == 2) ? v.z : v.w;
            bool p = (vj == k);
            unsigned long long mask = __ballot(p);
            if (p) queue[w][cnt + __popcll(mask & below_mask)] = rbase + j;
            cnt += __popcll(mask);
        }
        if (cnt >= QCAP - 256) DRAIN();
    }
    DRAIN();
#undef DRAIN

    redA[w][lane * 4 + 0] = a0;
    redA[w][lane * 4 + 1] = a1;
    redA[w][lane * 4 + 2] = a2;
    redA[w][lane * 4 + 3] = a3;
    #pragma unroll
    for (int m = 1; m < 64; m <<= 1) ls += __shfl_xor(ls, m, 64);
    if (lane == 0) { redL[w] = ls; redC[w] = tot; }
    __syncthreads();

    float dw = redA[0][tid] + redA[1][tid] + redA[2][tid] + redA[3][tid];
    dwT[(size_t)k * C_DIM + tid] = dw;
    if (tid == 0) {
        lossp[k] = redL[0] + redL[1] + redL[2] + redL[3];
        counts[k] = (float)(redC[0] + redC[1] + redC[2] + redC[3]);
    }
}

// ---------------- finalize 1: cs EMA, n, smoothing, entropy, loss ---------
// 1024 thr = 16 waves; wave shfl reductions + 16-partial LDS merge (3 barriers).
__global__ __launch_bounds__(1024) void finalize1_kernel(const float* __restrict__ ema_cs,
                                                         const float* __restrict__ counts,
                                                         const float* __restrict__ lossp,
                                                         float* __restrict__ out,
                                                         float* __restrict__ inv_sm) {
    __shared__ double partN[16], partE[16], partL[16];
    __shared__ float nf_sh;
    int k = threadIdx.x;
    int lane = k & 63, wid = k >> 6;

    float cs = counts[k];
    float necs = ema_cs[k] * DECAY_F + cs * ONE_MINUS_DECAY;
    out[OFF_CS + k] = necs;

    double vn = (double)necs;
    float avg = cs * (1.0f / (float)N_ROWS);
    double ve = (double)(avg * logf(avg + 1e-10f));
    double vl = (double)lossp[k];
    #pragma unroll
    for (int m = 1; m < 64; m <<= 1) {
        vn += __shfl_xor(vn, m, 64);
        ve += __shfl_xor(ve, m, 64);
        vl += __shfl_xor(vl, m, 64);
    }
    if (lane == 0) { partN[wid] = vn; partE[wid] = ve; partL[wid] = vl; }
    __syncthreads();
    if (k == 0) {
        double sn = 0.0, se = 0.0, sl = 0.0;
        #pragma unroll
        for (int i = 0; i < 16; ++i) { sn += partN[i]; se += partE[i]; sl += partL[i]; }
        nf_sh = (float)sn;
        double eloss = sl / (double)(N_ROWS * C_DIM);
        out[OFF_LOSS] = (float)(0.25 * eloss);
        out[OFF_PERP] = expf((float)(-se));
    }
    __syncthreads();
    float nf = nf_sh;
    float sm = (necs + EPS_F) / (nf + (float)K_CODES * EPS_F) * nf;
    inv_sm[k] = 1.0f / sm;
}

// ---------------- finalize 2: new_ema_dw, new_embeddings ----------------
__global__ __launch_bounds__(256) void finalize2_kernel(const float* __restrict__ ema_dw,
                                                        const float* __restrict__ dwT,
                                                        const float* __restrict__ inv_sm,
                                                        float* __restrict__ out) {
    int i = blockIdx.x * 256 + threadIdx.x;
    int c = i >> 10;
    int k = i & 1023;
    float ndw = ema_dw[i] * DECAY_F + dwT[k * C_DIM + c] * ONE_MINUS_DECAY;
    out[OFF_DW + i] = ndw;
    out[OFF_EMB + i] = ndw * inv_sm[k];
}

extern "C" void kernel_launch(void* const* d_in, const int* in_sizes, int n_in,
                              void* d_out, int out_size, void* d_ws, size_t ws_size,
                              hipStream_t stream) {
    const float* inputs = (const float*)d_in[0];
    const float* E      = (const float*)d_in[1];
    const float* ema_cs = (const float*)d_in[2];
    const float* ema_dw = (const float*)d_in[3];
    float* out = (float*)d_out;
    float* ws  = (float*)d_ws;

    float* esq    = ws + WS_ESQ;
    short* Bp     = (short*)(ws + WS_BP);
    float* dwT    = ws + WS_DWT;
    float* counts = ws + WS_CNT;
    float* lossp  = ws + WS_LOSSP;
    float* inv_sm = ws + WS_INVSM;
    int*   idxbuf = (int*)(ws + WS_IDX);

    prep_kernel<<<132, 256, 0, stream>>>(E, Bp, esq);
    mfma_dist_kernel<<<N_ROWS / 64, 512, 0, stream>>>(inputs, Bp, esq, idxbuf);
    percode_kernel<<<K_CODES, 256, 0, stream>>>(inputs, E, idxbuf, out + OFF_QST,
                                                dwT, counts, lossp);
    finalize1_kernel<<<1, 1024, 0, stream>>>(ema_cs, counts, lossp, out, inv_sm);
    finalize2_kernel<<<(C_DIM * K_CODES) / 256, 256, 0, stream>>>(ema_dw, dwT, inv_sm, out);
}